// Round 23
// baseline (226.120 us; speedup 1.0000x reference)
//
#include <hip/hip_runtime.h>
#include <hip/hip_bf16.h>
#include <math.h>

typedef __hip_bfloat16 bf16;
typedef __attribute__((ext_vector_type(8))) short short8;
typedef __attribute__((ext_vector_type(4))) float f32x4;
#define EPSF 1e-6f

__device__ __forceinline__ float b2f(bf16 v){ return __bfloat162float(v); }
__device__ __forceinline__ bf16  f2b(float v){ return __float2bfloat16(v); }
// fast softplus: abs err <3e-7 vs libm (verified absmax stable R8-R22).
__device__ __forceinline__ float spf(float x){ return x > 20.f ? x : __logf(1.f + __expf(x)); }
__device__ __forceinline__ float sigf(float x){ return 1.f/(1.f + __expf(-x)); }

__device__ __forceinline__ float wsum(float v){
#pragma unroll
  for (int m = 32; m; m >>= 1) v += __shfl_xor(v, m, 64);
  return v;
}
__device__ __forceinline__ float wmaxr(float v){
#pragma unroll
  for (int m = 32; m; m >>= 1) v = fmaxf(v, __shfl_xor(v, m, 64));
  return v;
}
__device__ __forceinline__ float wminr(float v){
#pragma unroll
  for (int m = 32; m; m >>= 1) v = fminf(v, __shfl_xor(v, m, 64));
  return v;
}
// two packed bf16 (as one u32's bits, given as float) -> two floats
__device__ __forceinline__ void unp(float fv, float& lo, float& hi){
  unsigned u = __float_as_uint(fv);
  lo = __uint_as_float(u << 16);
  hi = __uint_as_float(u & 0xffff0000u);
}

struct PrepArgs {
  const float* w0r[2]; const float* b0[2]; const float* w1r[2]; const float* b1[2];
  const float* zw[2];  const float* g0[2]; const float* g1[2]; const float* ob[2];
  const float* v;
  bf16* W0gB[2]; bf16* MtB[2]; float* b0g[2]; float* B1g[2]; float* obm[2];
  bf16* vT; float* aAcc;
};

// Fused prep (weights fold, blocks 0-511) + v transpose (blocks 512-767).
// Block 767 additionally zeroes a_acc (replaces the hipMemsetAsync launch).
__global__ __launch_bounds__(256) void prepv_kernel(PrepArgs a){
  int bid = blockIdx.x;
  if (bid < 512) {
    int idx = bid*256 + threadIdx.x;   // 0..131071
    int s = idx >> 16, r = idx & 65535;
    {
      int p = r >> 13;
      float g0 = sigf(a.g0[s][p]);
      float w  = spf(a.w0r[s][r]);
      a.W0gB[s][r] = f2b(g0 * w * w);
    }
    {
      int pd = r >> 7, kk = r & 127;
      int p = pd >> 6, d = pd & 63;
      float g1 = sigf(a.g1[s][p]);
      float w  = spf(a.w1r[s][r]);   // w1r[p,d,kk] flat == r
      float z  = a.zw[s][(p<<13) + (kk<<6) + d];
      a.MtB[s][r] = f2b(g1 * w * w + z);
    }
    if (r < 1024) a.b0g[s][r] = sigf(a.g0[s][r>>7]) * a.b0[s][r];
    if (r < 512)  a.B1g[s][r] = sigf(a.g1[s][r>>6]) * a.b1[s][r];
    if (r < 8) {
      float t = 0.f;
      for (int d = 0; d < 64; ++d) t += a.ob[s][r*64 + d];
      a.obm[s][r] = t * (1.f/64.f);
    }
  } else {
    // v[bh][j][d] fp32 -> vT[bh][d][j] bf16 (64x64 tiles via LDS)
    __shared__ float vL[64][65];
    int id2 = bid - 512;
    int bh = id2 >> 4, jt = id2 & 15;
    int j0 = jt * 64, t = threadIdx.x;
    if (bid == 767) {    // zero a_acc (8 KB) alongside the transpose
      for (int i = t; i < 2048; i += 256) a.aAcc[i] = 0.f;
    }
    for (int i = 0; i < 16; ++i) {
      int idx = t + i*256;
      int jj = idx >> 6, d = idx & 63;
      vL[jj][d] = a.v[((long)bh*1024 + j0 + jj)*64 + d];
    }
    __syncthreads();
    for (int i = 0; i < 16; ++i) {
      int idx = t + i*256;
      int dd = idx >> 6, js = idx & 63;
      a.vT[((long)bh*64 + dd)*1024 + j0 + js] = f2b(vL[js][dd]);
    }
  }
}

struct HullArgs {
  const float* x[2]; const float* gw[2]; const float* gb[2]; const float* wh[2];
  const bf16* W0gB[2]; const bf16* MtB[2];
  const float* b0g[2]; const float* B1g[2]; const float* obm[2];
  float* tauOut; float* fOut[2]; float* phiOut[2];
};

// MFMA hull (R11-proven, UNCHANGED): 16 rows/block, q+k fused.
__global__ __launch_bounds__(256) void hull_kernel(HullArgs A){
  __shared__ __align__(16) bf16 xgb[16][72];
  __shared__ __align__(16) bf16 z0[16][1032];
  __shared__ float tauh[16];
  __shared__ float scoreb[16][8];
  int bid = blockIdx.x;
  int s = bid >> 10;
  int isQ = (s == 0);
  long row0 = (long)(bid & 1023) * 16;
  const float* x   = A.x[s];
  const float* gw  = A.gw[s];
  const float* wh  = A.wh[s];
  const bf16* W0gB = A.W0gB[s];
  const bf16* MtB  = A.MtB[s];
  const float* b0g = A.b0g[s];
  const float* B1g = A.B1g[s];
  const float* obm = A.obm[s];
  float* fOut   = A.fOut[s];
  float* phiOut = A.phiOut[s];
  int t = threadIdx.x, lane = t & 63, w = t >> 6;
  float gbf = A.gb[s][0];

  for (int rp = 0; rp < 4; ++rp) {
    int r = rp*4 + w;
    long row = row0 + r;
    float xv = x[row*64 + lane];
    float xh = isQ ? xv * spf(xv) : xv;
    float s1 = wsum(xh * gw[lane]);
    float g = 1.f - __expf(-spf(s1 + gbf));
    float xgv = xh * g;
    float msq = wsum(xgv*xgv)*(1.f/64.f) + EPSF;
    float th = __expf(0.30343f*sqrtf(msq) + 0.22159f);
    if (lane == 0) tauh[r] = th;
    if (isQ) {
      float m2 = wsum(xh*xh)*(1.f/64.f) + EPSF;
      if (lane == 0) A.tauOut[row] = __expf(0.30343f*sqrtf(m2) + 0.22159f);
    }
    xgb[r][lane] = f2b(xgv);
    float myphi = 0.f;
#pragma unroll
    for (int jj = 0; jj < 16; ++jj) {
      float pv = wsum(xh * wh[jj*64 + lane]);
      if (lane == jj) myphi = pv;
    }
    if (lane < 16) phiOut[row*16 + lane] = spf(fminf(myphi, 20.f)) + EPSF;
  }
  __syncthreads();

  {
    int g = lane >> 4, cl = lane & 15;
    short8 a0 = *(const short8*)&xgb[cl][g*8];
    short8 a1 = *(const short8*)&xgb[cl][32 + g*8];
    for (int ct = 0; ct < 16; ++ct) {
      int col = w*256 + ct*16 + cl;
      const short8* bp = (const short8*)(W0gB + col*64);
      short8 b0 = bp[g];
      short8 b1 = bp[4 + g];
      f32x4 acc = {0.f, 0.f, 0.f, 0.f};
      acc = __builtin_amdgcn_mfma_f32_16x16x32_bf16(a0, b0, acc, 0, 0, 0);
      acc = __builtin_amdgcn_mfma_f32_16x16x32_bf16(a1, b1, acc, 0, 0, 0);
      float bb = b0g[col];
#pragma unroll
      for (int rg = 0; rg < 4; ++rg)
        z0[g*4 + rg][col] = f2b(spf(acc[rg] + bb));
    }
  }
  __syncthreads();

  {
    int g = lane >> 4, cl = lane & 15;
    for (int pi = 0; pi < 2; ++pi) {
      int p = w + pi*4;
      short8 af[4];
#pragma unroll
      for (int kc = 0; kc < 4; ++kc)
        af[kc] = *(const short8*)&z0[cl][p*128 + kc*32 + g*8];
      float s0 = 0.f, s1 = 0.f, s2 = 0.f, s3 = 0.f;
#pragma unroll
      for (int nt = 0; nt < 4; ++nt) {
        int dcol = nt*16 + cl;
        const short8* mp = (const short8*)(MtB + (p*64 + dcol)*128);
        f32x4 acc = {0.f, 0.f, 0.f, 0.f};
#pragma unroll
        for (int kc = 0; kc < 4; ++kc)
          acc = __builtin_amdgcn_mfma_f32_16x16x32_bf16(af[kc], mp[kc*4 + g], acc, 0, 0, 0);
        float bb = B1g[p*64 + dcol];
        s0 += spf(acc[0] + bb);
        s1 += spf(acc[1] + bb);
        s2 += spf(acc[2] + bb);
        s3 += spf(acc[3] + bb);
      }
#pragma unroll
      for (int m = 1; m < 16; m <<= 1) {
        s0 += __shfl_xor(s0, m, 64);
        s1 += __shfl_xor(s1, m, 64);
        s2 += __shfl_xor(s2, m, 64);
        s3 += __shfl_xor(s3, m, 64);
      }
      if (cl == 0) {
        scoreb[g*4+0][p] = s0 * (1.f/64.f);
        scoreb[g*4+1][p] = s1 * (1.f/64.f);
        scoreb[g*4+2][p] = s2 * (1.f/64.f);
        scoreb[g*4+3][p] = s3 * (1.f/64.f);
      }
    }
  }
  __syncthreads();

  if (t < 16) {
    int r = t;
    float th = tauh[r];
    float li[8]; float m = -1e30f;
#pragma unroll
    for (int p = 0; p < 8; ++p) { li[p] = (scoreb[r][p] + obm[p]) * th; m = fmaxf(m, li[p]); }
    float ssum = 0.f;
#pragma unroll
    for (int p = 0; p < 8; ++p) ssum += __expf(li[p] - m);
    fOut[row0 + r] = (m + __logf(ssum)) / th;
  }
}

// R20/R22-proven head-split attention. R23: waves 4-7 iterate phase-A j-tiles in
// REVERSE (cc = 15-c) -- bitwise-identical logits, halves the instantaneous phiK
// L1 working set per 4-wave group (panel 64KB vs 32KB L1).
__global__ __launch_bounds__(512) void attn5_kernel(
  const float* __restrict__ mask, const bf16* __restrict__ vT,
  const float* __restrict__ phiQ, const float* __restrict__ phiK,
  const float* __restrict__ fqA, const float* __restrict__ gkA, const float* __restrict__ tauA,
  float* __restrict__ smPart0, float* __restrict__ smPart1, float* __restrict__ outO)
{
  __shared__ __align__(16) bf16 ebf[16][1032];   // rows 0-7 valid; 8-15 zeroed
  __shared__ __align__(16) float smp[8][1024];   // partial Sum_h w (4 heads)
  __shared__ float phq[8][16];
  __shared__ float fqs[8], taus[8], sinvL[8];
  int t = threadIdx.x, lane = t & 63, w = t >> 6;
  int b = blockIdx.x >> 8, hg = (blockIdx.x >> 7) & 1, it = blockIdx.x & 127;
  int i0 = it * 8;

  {
    float* z = (float*)&ebf[8][0];
    for (int idx = t; idx < 4128; idx += 512) z[idx] = 0.f;
  }

  for (int h = 0; h < 4; ++h) {
    int bh = b*8 + hg*4 + h;
    long pbase = (long)bh * 1024;
    if (t < 128) { int r = t >> 4, c = t & 15;
      phq[r][c] = phiQ[(pbase + i0 + r)*16 + c]; }
    else if (t < 136) { int r = t - 128; fqs[r] = fqA[pbase + i0 + r]; }
    else if (t < 144) { int r = t - 136; taus[r] = tauA[pbase + i0 + r]; }
    __syncthreads();   // stages visible; prev head's ebf/smp readers done

    // ---- phase A: wave w owns row i0+w; 16 logits per lane in regs ----
    float l[16];
    {
      float pq[16];
#pragma unroll
      for (int c = 0; c < 16; ++c) pq[c] = phq[w][c];
      float fq = fqs[w], ta = taus[w];
      const float* pkb = phiK + pbase*16;
      const float* mrow = mask + (pbase + i0 + w)*1024;
      const float* gkb = gkA + pbase;
      int rev = (w >= 4);
#pragma unroll 4
      for (int c = 0; c < 16; ++c) {
        int cc = rev ? (15 - c) : c;      // direction split: L1-friendlier
        int j = cc*64 + lane;
        const float4* pk = (const float4*)(pkb + j*16);
        float4 k0 = pk[0], k1 = pk[1], k2 = pk[2], k3 = pk[3];
        float dp = pq[0]*k0.x + pq[1]*k0.y + pq[2]*k0.z + pq[3]*k0.w
                 + pq[4]*k1.x + pq[5]*k1.y + pq[6]*k1.z + pq[7]*k1.w
                 + pq[8]*k2.x + pq[9]*k2.y + pq[10]*k2.z + pq[11]*k2.w
                 + pq[12]*k3.x + pq[13]*k3.y + pq[14]*k3.z + pq[15]*k3.w;
        float mk = fmaxf(mrow[j], EPSF);
        l[cc] = (fq + gkb[j] + __logf(dp * mk)) * ta;
      }
    }
    // ---- softmax (wave-internal); e -> bf16 LDS ----
    {
      float m = -1e30f;
#pragma unroll
      for (int c = 0; c < 16; ++c) m = fmaxf(m, l[c]);
      m = wmaxr(m);
      float s = 0.f;
#pragma unroll
      for (int c = 0; c < 16; ++c) {
        float e = __expf(l[c] - m);
        s += e;
        ebf[w][c*64 + lane] = f2b(e);
      }
      s = wsum(s);
      if (lane == 0) sinvL[w] = 1.f / s;
    }
    __syncthreads();   // ebf + sinvL ready

    if (w < 4) {
      // ---- PV via MFMA (R16-proven mapping): wave w owns d-tile w ----
      int g = lane >> 4, cl = lane & 15;
      const short8* bp = (const short8*)(vT + ((long)bh*64 + w*16 + cl)*1024);
      f32x4 cf = {0.f, 0.f, 0.f, 0.f};
      for (int kc = 0; kc < 32; ++kc) {
        short8 aF = *(const short8*)&ebf[cl][kc*32 + g*8];
        short8 bF = bp[kc*4 + g];
        cf = __builtin_amdgcn_mfma_f32_16x16x32_bf16(aF, bF, cf, 0, 0, 0);
      }
      if (g < 2) {
#pragma unroll
        for (int i = 0; i < 4; ++i) {
          int row = g*4 + i;     // 0..7 valid
          outO[(pbase + i0 + row)*64 + w*16 + cl] = cf[i] * sinvL[row];
        }
      }
    } else {
      // ---- partial Sum_h w accumulation (waves 4-7) ----
      int r0 = (w-4)*2;
#pragma unroll
      for (int rr = 0; rr < 2; ++rr) {
        int r = r0 + rr;
        float sv = sinvL[r];
#pragma unroll
        for (int ch = 0; ch < 4; ++ch) {
          int jb = ch*256 + lane*4;
          uint2 eb = *(const uint2*)&ebf[r][jb];
          float e0,e1,e2,e3;
          unp(__uint_as_float(eb.x), e0, e1);
          unp(__uint_as_float(eb.y), e2, e3);
          float4 acc;
          if (h == 0) acc = make_float4(0.f,0.f,0.f,0.f);
          else        acc = *(float4*)&smp[r][jb];
          acc.x += sv*e0; acc.y += sv*e1; acc.z += sv*e2; acc.w += sv*e3;
          *(float4*)&smp[r][jb] = acc;
        }
      }
    }
    __syncthreads();   // protect ebf/sinvL/smp for next head
  }

  // ---- write 4-head partial to global (plain stores, disjoint per hg) ----
  {
    float* dst = (hg == 0 ? smPart0 : smPart1) + ((long)b*1024 + i0)*1024;
    for (int idx = t; idx < 2048; idx += 512) {
      int r = idx >> 8, j4 = (idx & 255)*4;
      *(float4*)&dst[(long)r*1024 + j4] = *(const float4*)&smp[r][j4];
    }
  }
}

// Combine the two head-group partials, row-softmax, mean over i (R20-proven).
__global__ __launch_bounds__(256) void smsoft_kernel(
  const float* __restrict__ p0, const float* __restrict__ p1, float* __restrict__ aAcc)
{
  int b = blockIdx.x >> 7, ii = blockIdx.x & 127;
  int t = threadIdx.x, lane = t & 63, w = t >> 6;
  __shared__ float redm[4], reds[4];
  float a0 = 0.f, a1 = 0.f, a2 = 0.f, a3 = 0.f;
  for (int i = 0; i < 8; ++i) {
    long row = ((long)b*1024 + ii*8 + i)*1024 + t*4;
    float4 v0 = *(const float4*)(p0 + row);
    float4 v1 = *(const float4*)(p1 + row);
    float4 v = make_float4(v0.x+v1.x, v0.y+v1.y, v0.z+v1.z, v0.w+v1.w);
    float m = fmaxf(fmaxf(v.x, v.y), fmaxf(v.z, v.w));
    m = wmaxr(m);
    if (lane == 0) redm[w] = m;
    __syncthreads();
    m = fmaxf(fmaxf(redm[0], redm[1]), fmaxf(redm[2], redm[3]));
    float4 e;
    e.x = __expf(v.x - m); e.y = __expf(v.y - m); e.z = __expf(v.z - m); e.w = __expf(v.w - m);
    float s = e.x + e.y + e.z + e.w;
    s = wsum(s);
    if (lane == 0) reds[w] = s;
    __syncthreads();
    s = reds[0] + reds[1] + reds[2] + reds[3];
    float inv = 1.f / (s * 1024.f);
    a0 += e.x*inv; a1 += e.y*inv; a2 += e.z*inv; a3 += e.w*inv;
    __syncthreads();
  }
  atomicAdd(&aAcc[b*1024 + t*4+0], a0);
  atomicAdd(&aAcc[b*1024 + t*4+1], a1);
  atomicAdd(&aAcc[b*1024 + t*4+2], a2);
  atomicAdd(&aAcc[b*1024 + t*4+3], a3);
}

// min-max normalize a, write fp32
__global__ __launch_bounds__(1024) void anorm_kernel(const float* __restrict__ aAcc, float* __restrict__ outA){
  int b = blockIdx.x, t = threadIdx.x, lane = t & 63, w = t >> 6;
  float v = aAcc[b*1024 + t];
  __shared__ float rmn[16], rmx[16];
  float mn = wminr(v), mx = wmaxr(v);
  if (lane == 0) { rmn[w] = mn; rmx[w] = mx; }
  __syncthreads();
  mn = rmn[0]; mx = rmx[0];
#pragma unroll
  for (int i = 1; i < 16; ++i) { mn = fminf(mn, rmn[i]); mx = fmaxf(mx, rmx[i]); }
  outA[b*1024 + t] = (v - mn) / (mx - mn + EPSF);
}

extern "C" void kernel_launch(void* const* d_in, const int* in_sizes, int n_in,
                              void* d_out, int out_size, void* d_ws, size_t ws_size,
                              hipStream_t stream)
{
  (void)in_sizes; (void)n_in; (void)out_size; (void)ws_size;
  const float* q    = (const float*)d_in[0];
  const float* k    = (const float*)d_in[1];
  const float* v    = (const float*)d_in[2];
  const float* mask = (const float*)d_in[3];
  const float* whq  = (const float*)d_in[4];
  const float* whk  = (const float*)d_in[5];

  float* ws = (float*)d_ws;          // total ~21.7 MB (fit proven R19-R22)
  bf16* w0b_q = (bf16*)(ws);
  bf16* w0b_k = (bf16*)(ws + 32768);
  bf16* mtb_q = (bf16*)(ws + 65536);
  bf16* mtb_k = (bf16*)(ws + 98304);
  float* b0g_q = ws + 131072;
  float* b0g_k = ws + 132096;
  float* B1g_q = ws + 133120;
  float* B1g_k = ws + 133632;
  float* obm_q = ws + 134144;
  float* obm_k = ws + 134160;
  float* tau_q = ws + 134176;
  float* fq_a  = ws + 150560;
  float* gk_a  = ws + 166944;
  float* phi_q = ws + 183328;
  float* phi_k = ws + 445472;
  bf16*  v_T   = (bf16*)(ws + 707616);   // 1,048,576 bf16 = 524,288 fl
  float* a_acc = ws + 1231904;           // 2048
  float* smP0  = ws + 1233952;           // 2,097,152
  float* smP1  = ws + 3331104;           // 2,097,152

  PrepArgs pa;
  for (int s = 0; s < 2; ++s) {
    int o = 6 + 10*s;
    pa.w0r[s] = (const float*)d_in[o+0];
    pa.b0 [s] = (const float*)d_in[o+1];
    pa.w1r[s] = (const float*)d_in[o+2];
    pa.b1 [s] = (const float*)d_in[o+3];
    pa.zw [s] = (const float*)d_in[o+4];
    pa.g0 [s] = (const float*)d_in[o+5];
    pa.g1 [s] = (const float*)d_in[o+6];
    pa.ob [s] = (const float*)d_in[o+7];
  }
  pa.v = v;
  pa.W0gB[0]=w0b_q; pa.W0gB[1]=w0b_k; pa.MtB[0]=mtb_q; pa.MtB[1]=mtb_k;
  pa.b0g[0]=b0g_q; pa.b0g[1]=b0g_k; pa.B1g[0]=B1g_q; pa.B1g[1]=B1g_k;
  pa.obm[0]=obm_q; pa.obm[1]=obm_k;
  pa.vT = v_T;
  pa.aAcc = a_acc;

  prepv_kernel<<<768,256,0,stream>>>(pa);

  HullArgs ha;
  ha.x[0] = q; ha.x[1] = k;
  ha.gw[0] = (const float*)d_in[14]; ha.gw[1] = (const float*)d_in[24];
  ha.gb[0] = (const float*)d_in[15]; ha.gb[1] = (const float*)d_in[25];
  ha.wh[0] = whq; ha.wh[1] = whk;
  ha.W0gB[0] = w0b_q; ha.W0gB[1] = w0b_k;
  ha.MtB[0] = mtb_q;  ha.MtB[1] = mtb_k;
  ha.b0g[0] = b0g_q;  ha.b0g[1] = b0g_k;
  ha.B1g[0] = B1g_q;  ha.B1g[1] = B1g_k;
  ha.obm[0] = obm_q;  ha.obm[1] = obm_k;
  ha.tauOut = tau_q;
  ha.fOut[0] = fq_a;  ha.fOut[1] = gk_a;
  ha.phiOut[0] = phi_q; ha.phiOut[1] = phi_k;

  hull_kernel<<<2048,256,0,stream>>>(ha);

  attn5_kernel<<<512,512,0,stream>>>(mask, v_T, phi_q, phi_k, fq_a, gk_a, tau_q,
                                     smP0, smP1, (float*)d_out);
  smsoft_kernel<<<256,256,0,stream>>>(smP0, smP1, a_acc);
  anorm_kernel<<<2,1024,0,stream>>>(a_acc, (float*)d_out + 1048576);
}

// Round 24
// 212.892 us; speedup vs baseline: 1.0621x; 1.0621x over previous
//
#include <hip/hip_runtime.h>
#include <hip/hip_bf16.h>
#include <math.h>

typedef __hip_bfloat16 bf16;
typedef __attribute__((ext_vector_type(8))) short short8;
typedef __attribute__((ext_vector_type(4))) float f32x4;
#define EPSF 1e-6f

__device__ __forceinline__ float b2f(bf16 v){ return __bfloat162float(v); }
__device__ __forceinline__ bf16  f2b(float v){ return __float2bfloat16(v); }
// fast softplus: abs err <3e-7 vs libm (verified absmax stable R8-R23).
__device__ __forceinline__ float spf(float x){ return x > 20.f ? x : __logf(1.f + __expf(x)); }
__device__ __forceinline__ float sigf(float x){ return 1.f/(1.f + __expf(-x)); }

__device__ __forceinline__ float wsum(float v){
#pragma unroll
  for (int m = 32; m; m >>= 1) v += __shfl_xor(v, m, 64);
  return v;
}
__device__ __forceinline__ float wmaxr(float v){
#pragma unroll
  for (int m = 32; m; m >>= 1) v = fmaxf(v, __shfl_xor(v, m, 64));
  return v;
}
__device__ __forceinline__ float wminr(float v){
#pragma unroll
  for (int m = 32; m; m >>= 1) v = fminf(v, __shfl_xor(v, m, 64));
  return v;
}
// two packed bf16 (as one u32's bits, given as float) -> two floats
__device__ __forceinline__ void unp(float fv, float& lo, float& hi){
  unsigned u = __float_as_uint(fv);
  lo = __uint_as_float(u << 16);
  hi = __uint_as_float(u & 0xffff0000u);
}

struct PrepArgs {
  const float* w0r[2]; const float* b0[2]; const float* w1r[2]; const float* b1[2];
  const float* zw[2];  const float* g0[2]; const float* g1[2]; const float* ob[2];
  const float* v;
  bf16* W0gB[2]; bf16* MtB[2]; float* b0g[2]; float* B1g[2]; float* obm[2];
  bf16* vT; float* aAcc;
};

// Fused prep (weights fold, blocks 0-511) + v transpose (blocks 512-767).
// Block 767 additionally zeroes a_acc (replaces the hipMemsetAsync launch).
__global__ __launch_bounds__(256) void prepv_kernel(PrepArgs a){
  int bid = blockIdx.x;
  if (bid < 512) {
    int idx = bid*256 + threadIdx.x;   // 0..131071
    int s = idx >> 16, r = idx & 65535;
    {
      int p = r >> 13;
      float g0 = sigf(a.g0[s][p]);
      float w  = spf(a.w0r[s][r]);
      a.W0gB[s][r] = f2b(g0 * w * w);
    }
    {
      int pd = r >> 7, kk = r & 127;
      int p = pd >> 6, d = pd & 63;
      float g1 = sigf(a.g1[s][p]);
      float w  = spf(a.w1r[s][r]);   // w1r[p,d,kk] flat == r
      float z  = a.zw[s][(p<<13) + (kk<<6) + d];
      a.MtB[s][r] = f2b(g1 * w * w + z);
    }
    if (r < 1024) a.b0g[s][r] = sigf(a.g0[s][r>>7]) * a.b0[s][r];
    if (r < 512)  a.B1g[s][r] = sigf(a.g1[s][r>>6]) * a.b1[s][r];
    if (r < 8) {
      float t = 0.f;
      for (int d = 0; d < 64; ++d) t += a.ob[s][r*64 + d];
      a.obm[s][r] = t * (1.f/64.f);
    }
  } else {
    // v[bh][j][d] fp32 -> vT[bh][d][j] bf16 (64x64 tiles via LDS)
    __shared__ float vL[64][65];
    int id2 = bid - 512;
    int bh = id2 >> 4, jt = id2 & 15;
    int j0 = jt * 64, t = threadIdx.x;
    if (bid == 767) {    // zero a_acc (8 KB) alongside the transpose
      for (int i = t; i < 2048; i += 256) a.aAcc[i] = 0.f;
    }
    for (int i = 0; i < 16; ++i) {
      int idx = t + i*256;
      int jj = idx >> 6, d = idx & 63;
      vL[jj][d] = a.v[((long)bh*1024 + j0 + jj)*64 + d];
    }
    __syncthreads();
    for (int i = 0; i < 16; ++i) {
      int idx = t + i*256;
      int dd = idx >> 6, js = idx & 63;
      a.vT[((long)bh*64 + dd)*1024 + j0 + js] = f2b(vL[js][dd]);
    }
  }
}

struct HullArgs {
  const float* x[2]; const float* gw[2]; const float* gb[2]; const float* wh[2];
  const bf16* W0gB[2]; const bf16* MtB[2];
  const float* b0g[2]; const float* B1g[2]; const float* obm[2];
  float* tauOut; float* fOut[2]; float* phiOut[2];
};

// MFMA hull (R11-proven, UNCHANGED): 16 rows/block, q+k fused.
__global__ __launch_bounds__(256) void hull_kernel(HullArgs A){
  __shared__ __align__(16) bf16 xgb[16][72];
  __shared__ __align__(16) bf16 z0[16][1032];
  __shared__ float tauh[16];
  __shared__ float scoreb[16][8];
  int bid = blockIdx.x;
  int s = bid >> 10;
  int isQ = (s == 0);
  long row0 = (long)(bid & 1023) * 16;
  const float* x   = A.x[s];
  const float* gw  = A.gw[s];
  const float* wh  = A.wh[s];
  const bf16* W0gB = A.W0gB[s];
  const bf16* MtB  = A.MtB[s];
  const float* b0g = A.b0g[s];
  const float* B1g = A.B1g[s];
  const float* obm = A.obm[s];
  float* fOut   = A.fOut[s];
  float* phiOut = A.phiOut[s];
  int t = threadIdx.x, lane = t & 63, w = t >> 6;
  float gbf = A.gb[s][0];

  for (int rp = 0; rp < 4; ++rp) {
    int r = rp*4 + w;
    long row = row0 + r;
    float xv = x[row*64 + lane];
    float xh = isQ ? xv * spf(xv) : xv;
    float s1 = wsum(xh * gw[lane]);
    float g = 1.f - __expf(-spf(s1 + gbf));
    float xgv = xh * g;
    float msq = wsum(xgv*xgv)*(1.f/64.f) + EPSF;
    float th = __expf(0.30343f*sqrtf(msq) + 0.22159f);
    if (lane == 0) tauh[r] = th;
    if (isQ) {
      float m2 = wsum(xh*xh)*(1.f/64.f) + EPSF;
      if (lane == 0) A.tauOut[row] = __expf(0.30343f*sqrtf(m2) + 0.22159f);
    }
    xgb[r][lane] = f2b(xgv);
    float myphi = 0.f;
#pragma unroll
    for (int jj = 0; jj < 16; ++jj) {
      float pv = wsum(xh * wh[jj*64 + lane]);
      if (lane == jj) myphi = pv;
    }
    if (lane < 16) phiOut[row*16 + lane] = spf(fminf(myphi, 20.f)) + EPSF;
  }
  __syncthreads();

  {
    int g = lane >> 4, cl = lane & 15;
    short8 a0 = *(const short8*)&xgb[cl][g*8];
    short8 a1 = *(const short8*)&xgb[cl][32 + g*8];
    for (int ct = 0; ct < 16; ++ct) {
      int col = w*256 + ct*16 + cl;
      const short8* bp = (const short8*)(W0gB + col*64);
      short8 b0 = bp[g];
      short8 b1 = bp[4 + g];
      f32x4 acc = {0.f, 0.f, 0.f, 0.f};
      acc = __builtin_amdgcn_mfma_f32_16x16x32_bf16(a0, b0, acc, 0, 0, 0);
      acc = __builtin_amdgcn_mfma_f32_16x16x32_bf16(a1, b1, acc, 0, 0, 0);
      float bb = b0g[col];
#pragma unroll
      for (int rg = 0; rg < 4; ++rg)
        z0[g*4 + rg][col] = f2b(spf(acc[rg] + bb));
    }
  }
  __syncthreads();

  {
    int g = lane >> 4, cl = lane & 15;
    for (int pi = 0; pi < 2; ++pi) {
      int p = w + pi*4;
      short8 af[4];
#pragma unroll
      for (int kc = 0; kc < 4; ++kc)
        af[kc] = *(const short8*)&z0[cl][p*128 + kc*32 + g*8];
      float s0 = 0.f, s1 = 0.f, s2 = 0.f, s3 = 0.f;
#pragma unroll
      for (int nt = 0; nt < 4; ++nt) {
        int dcol = nt*16 + cl;
        const short8* mp = (const short8*)(MtB + (p*64 + dcol)*128);
        f32x4 acc = {0.f, 0.f, 0.f, 0.f};
#pragma unroll
        for (int kc = 0; kc < 4; ++kc)
          acc = __builtin_amdgcn_mfma_f32_16x16x32_bf16(af[kc], mp[kc*4 + g], acc, 0, 0, 0);
        float bb = B1g[p*64 + dcol];
        s0 += spf(acc[0] + bb);
        s1 += spf(acc[1] + bb);
        s2 += spf(acc[2] + bb);
        s3 += spf(acc[3] + bb);
      }
#pragma unroll
      for (int m = 1; m < 16; m <<= 1) {
        s0 += __shfl_xor(s0, m, 64);
        s1 += __shfl_xor(s1, m, 64);
        s2 += __shfl_xor(s2, m, 64);
        s3 += __shfl_xor(s3, m, 64);
      }
      if (cl == 0) {
        scoreb[g*4+0][p] = s0 * (1.f/64.f);
        scoreb[g*4+1][p] = s1 * (1.f/64.f);
        scoreb[g*4+2][p] = s2 * (1.f/64.f);
        scoreb[g*4+3][p] = s3 * (1.f/64.f);
      }
    }
  }
  __syncthreads();

  if (t < 16) {
    int r = t;
    float th = tauh[r];
    float li[8]; float m = -1e30f;
#pragma unroll
    for (int p = 0; p < 8; ++p) { li[p] = (scoreb[r][p] + obm[p]) * th; m = fmaxf(m, li[p]); }
    float ssum = 0.f;
#pragma unroll
    for (int p = 0; p < 8; ++p) ssum += __expf(li[p] - m);
    fOut[row0 + r] = (m + __logf(ssum)) / th;
  }
}

// R22-proven head-split attention (forward iteration, static indices, unroll 4).
__global__ __launch_bounds__(512) void attn5_kernel(
  const float* __restrict__ mask, const bf16* __restrict__ vT,
  const float* __restrict__ phiQ, const float* __restrict__ phiK,
  const float* __restrict__ fqA, const float* __restrict__ gkA, const float* __restrict__ tauA,
  float* __restrict__ smPart0, float* __restrict__ smPart1, float* __restrict__ outO)
{
  __shared__ __align__(16) bf16 ebf[16][1032];   // rows 0-7 valid; 8-15 zeroed
  __shared__ __align__(16) float smp[8][1024];   // partial Sum_h w (4 heads)
  __shared__ float phq[8][16];
  __shared__ float fqs[8], taus[8], sinvL[8];
  int t = threadIdx.x, lane = t & 63, w = t >> 6;
  int b = blockIdx.x >> 8, hg = (blockIdx.x >> 7) & 1, it = blockIdx.x & 127;
  int i0 = it * 8;

  {
    float* z = (float*)&ebf[8][0];
    for (int idx = t; idx < 4128; idx += 512) z[idx] = 0.f;
  }

  for (int h = 0; h < 4; ++h) {
    int bh = b*8 + hg*4 + h;
    long pbase = (long)bh * 1024;
    if (t < 128) { int r = t >> 4, c = t & 15;
      phq[r][c] = phiQ[(pbase + i0 + r)*16 + c]; }
    else if (t < 136) { int r = t - 128; fqs[r] = fqA[pbase + i0 + r]; }
    else if (t < 144) { int r = t - 136; taus[r] = tauA[pbase + i0 + r]; }
    __syncthreads();   // stages visible; prev head's ebf/smp readers done

    // ---- phase A: wave w owns row i0+w; 16 logits per lane in regs ----
    float l[16];
    {
      float pq[16];
#pragma unroll
      for (int c = 0; c < 16; ++c) pq[c] = phq[w][c];
      float fq = fqs[w], ta = taus[w];
      const float* pkb = phiK + pbase*16;
      const float* mrow = mask + (pbase + i0 + w)*1024;
      const float* gkb = gkA + pbase;
#pragma unroll 4
      for (int c = 0; c < 16; ++c) {
        int j = c*64 + lane;
        const float4* pk = (const float4*)(pkb + j*16);
        float4 k0 = pk[0], k1 = pk[1], k2 = pk[2], k3 = pk[3];
        float dp = pq[0]*k0.x + pq[1]*k0.y + pq[2]*k0.z + pq[3]*k0.w
                 + pq[4]*k1.x + pq[5]*k1.y + pq[6]*k1.z + pq[7]*k1.w
                 + pq[8]*k2.x + pq[9]*k2.y + pq[10]*k2.z + pq[11]*k2.w
                 + pq[12]*k3.x + pq[13]*k3.y + pq[14]*k3.z + pq[15]*k3.w;
        float mk = fmaxf(mrow[j], EPSF);
        l[c] = (fq + gkb[j] + __logf(dp * mk)) * ta;
      }
    }
    // ---- softmax (wave-internal); e -> bf16 LDS ----
    {
      float m = -1e30f;
#pragma unroll
      for (int c = 0; c < 16; ++c) m = fmaxf(m, l[c]);
      m = wmaxr(m);
      float s = 0.f;
#pragma unroll
      for (int c = 0; c < 16; ++c) {
        float e = __expf(l[c] - m);
        s += e;
        ebf[w][c*64 + lane] = f2b(e);
      }
      s = wsum(s);
      if (lane == 0) sinvL[w] = 1.f / s;
    }
    __syncthreads();   // ebf + sinvL ready

    if (w < 4) {
      // ---- PV via MFMA (R16-proven mapping): wave w owns d-tile w ----
      int g = lane >> 4, cl = lane & 15;
      const short8* bp = (const short8*)(vT + ((long)bh*64 + w*16 + cl)*1024);
      f32x4 cf = {0.f, 0.f, 0.f, 0.f};
      for (int kc = 0; kc < 32; ++kc) {
        short8 aF = *(const short8*)&ebf[cl][kc*32 + g*8];
        short8 bF = bp[kc*4 + g];
        cf = __builtin_amdgcn_mfma_f32_16x16x32_bf16(aF, bF, cf, 0, 0, 0);
      }
      if (g < 2) {
#pragma unroll
        for (int i = 0; i < 4; ++i) {
          int row = g*4 + i;     // 0..7 valid
          outO[(pbase + i0 + row)*64 + w*16 + cl] = cf[i] * sinvL[row];
        }
      }
    } else {
      // ---- partial Sum_h w accumulation (waves 4-7) ----
      int r0 = (w-4)*2;
#pragma unroll
      for (int rr = 0; rr < 2; ++rr) {
        int r = r0 + rr;
        float sv = sinvL[r];
#pragma unroll
        for (int ch = 0; ch < 4; ++ch) {
          int jb = ch*256 + lane*4;
          uint2 eb = *(const uint2*)&ebf[r][jb];
          float e0,e1,e2,e3;
          unp(__uint_as_float(eb.x), e0, e1);
          unp(__uint_as_float(eb.y), e2, e3);
          float4 acc;
          if (h == 0) acc = make_float4(0.f,0.f,0.f,0.f);
          else        acc = *(float4*)&smp[r][jb];
          acc.x += sv*e0; acc.y += sv*e1; acc.z += sv*e2; acc.w += sv*e3;
          *(float4*)&smp[r][jb] = acc;
        }
      }
    }
    __syncthreads();   // protect ebf/sinvL/smp for next head
  }

  // ---- write 4-head partial to global (plain stores, disjoint per hg) ----
  {
    float* dst = (hg == 0 ? smPart0 : smPart1) + ((long)b*1024 + i0)*1024;
    for (int idx = t; idx < 2048; idx += 512) {
      int r = idx >> 8, j4 = (idx & 255)*4;
      *(float4*)&dst[(long)r*1024 + j4] = *(const float4*)&smp[r][j4];
    }
  }
}

// Combine the two head-group partials, row-softmax, mean over i (R20-proven).
__global__ __launch_bounds__(256) void smsoft_kernel(
  const float* __restrict__ p0, const float* __restrict__ p1, float* __restrict__ aAcc)
{
  int b = blockIdx.x >> 7, ii = blockIdx.x & 127;
  int t = threadIdx.x, lane = t & 63, w = t >> 6;
  __shared__ float redm[4], reds[4];
  float a0 = 0.f, a1 = 0.f, a2 = 0.f, a3 = 0.f;
  for (int i = 0; i < 8; ++i) {
    long row = ((long)b*1024 + ii*8 + i)*1024 + t*4;
    float4 v0 = *(const float4*)(p0 + row);
    float4 v1 = *(const float4*)(p1 + row);
    float4 v = make_float4(v0.x+v1.x, v0.y+v1.y, v0.z+v1.z, v0.w+v1.w);
    float m = fmaxf(fmaxf(v.x, v.y), fmaxf(v.z, v.w));
    m = wmaxr(m);
    if (lane == 0) redm[w] = m;
    __syncthreads();
    m = fmaxf(fmaxf(redm[0], redm[1]), fmaxf(redm[2], redm[3]));
    float4 e;
    e.x = __expf(v.x - m); e.y = __expf(v.y - m); e.z = __expf(v.z - m); e.w = __expf(v.w - m);
    float s = e.x + e.y + e.z + e.w;
    s = wsum(s);
    if (lane == 0) reds[w] = s;
    __syncthreads();
    s = reds[0] + reds[1] + reds[2] + reds[3];
    float inv = 1.f / (s * 1024.f);
    a0 += e.x*inv; a1 += e.y*inv; a2 += e.z*inv; a3 += e.w*inv;
    __syncthreads();
  }
  atomicAdd(&aAcc[b*1024 + t*4+0], a0);
  atomicAdd(&aAcc[b*1024 + t*4+1], a1);
  atomicAdd(&aAcc[b*1024 + t*4+2], a2);
  atomicAdd(&aAcc[b*1024 + t*4+3], a3);
}

// min-max normalize a, write fp32
__global__ __launch_bounds__(1024) void anorm_kernel(const float* __restrict__ aAcc, float* __restrict__ outA){
  int b = blockIdx.x, t = threadIdx.x, lane = t & 63, w = t >> 6;
  float v = aAcc[b*1024 + t];
  __shared__ float rmn[16], rmx[16];
  float mn = wminr(v), mx = wmaxr(v);
  if (lane == 0) { rmn[w] = mn; rmx[w] = mx; }
  __syncthreads();
  mn = rmn[0]; mx = rmx[0];
#pragma unroll
  for (int i = 1; i < 16; ++i) { mn = fminf(mn, rmn[i]); mx = fmaxf(mx, rmx[i]); }
  outA[b*1024 + t] = (v - mn) / (mx - mn + EPSF);
}

extern "C" void kernel_launch(void* const* d_in, const int* in_sizes, int n_in,
                              void* d_out, int out_size, void* d_ws, size_t ws_size,
                              hipStream_t stream)
{
  (void)in_sizes; (void)n_in; (void)out_size; (void)ws_size;
  const float* q    = (const float*)d_in[0];
  const float* k    = (const float*)d_in[1];
  const float* v    = (const float*)d_in[2];
  const float* mask = (const float*)d_in[3];
  const float* whq  = (const float*)d_in[4];
  const float* whk  = (const float*)d_in[5];

  float* ws = (float*)d_ws;          // total ~21.7 MB (fit proven R19-R23)
  bf16* w0b_q = (bf16*)(ws);
  bf16* w0b_k = (bf16*)(ws + 32768);
  bf16* mtb_q = (bf16*)(ws + 65536);
  bf16* mtb_k = (bf16*)(ws + 98304);
  float* b0g_q = ws + 131072;
  float* b0g_k = ws + 132096;
  float* B1g_q = ws + 133120;
  float* B1g_k = ws + 133632;
  float* obm_q = ws + 134144;
  float* obm_k = ws + 134160;
  float* tau_q = ws + 134176;
  float* fq_a  = ws + 150560;
  float* gk_a  = ws + 166944;
  float* phi_q = ws + 183328;
  float* phi_k = ws + 445472;
  bf16*  v_T   = (bf16*)(ws + 707616);   // 1,048,576 bf16 = 524,288 fl
  float* a_acc = ws + 1231904;           // 2048
  float* smP0  = ws + 1233952;           // 2,097,152
  float* smP1  = ws + 3331104;           // 2,097,152

  PrepArgs pa;
  for (int s = 0; s < 2; ++s) {
    int o = 6 + 10*s;
    pa.w0r[s] = (const float*)d_in[o+0];
    pa.b0 [s] = (const float*)d_in[o+1];
    pa.w1r[s] = (const float*)d_in[o+2];
    pa.b1 [s] = (const float*)d_in[o+3];
    pa.zw [s] = (const float*)d_in[o+4];
    pa.g0 [s] = (const float*)d_in[o+5];
    pa.g1 [s] = (const float*)d_in[o+6];
    pa.ob [s] = (const float*)d_in[o+7];
  }
  pa.v = v;
  pa.W0gB[0]=w0b_q; pa.W0gB[1]=w0b_k; pa.MtB[0]=mtb_q; pa.MtB[1]=mtb_k;
  pa.b0g[0]=b0g_q; pa.b0g[1]=b0g_k; pa.B1g[0]=B1g_q; pa.B1g[1]=B1g_k;
  pa.obm[0]=obm_q; pa.obm[1]=obm_k;
  pa.vT = v_T;
  pa.aAcc = a_acc;

  prepv_kernel<<<768,256,0,stream>>>(pa);

  HullArgs ha;
  ha.x[0] = q; ha.x[1] = k;
  ha.gw[0] = (const float*)d_in[14]; ha.gw[1] = (const float*)d_in[24];
  ha.gb[0] = (const float*)d_in[15]; ha.gb[1] = (const float*)d_in[25];
  ha.wh[0] = whq; ha.wh[1] = whk;
  ha.W0gB[0] = w0b_q; ha.W0gB[1] = w0b_k;
  ha.MtB[0] = mtb_q;  ha.MtB[1] = mtb_k;
  ha.b0g[0] = b0g_q;  ha.b0g[1] = b0g_k;
  ha.B1g[0] = B1g_q;  ha.B1g[1] = B1g_k;
  ha.obm[0] = obm_q;  ha.obm[1] = obm_k;
  ha.tauOut = tau_q;
  ha.fOut[0] = fq_a;  ha.fOut[1] = gk_a;
  ha.phiOut[0] = phi_q; ha.phiOut[1] = phi_k;

  hull_kernel<<<2048,256,0,stream>>>(ha);

  attn5_kernel<<<512,512,0,stream>>>(mask, v_T, phi_q, phi_k, fq_a, gk_a, tau_q,
                                     smP0, smP1, (float*)d_out);
  smsoft_kernel<<<256,256,0,stream>>>(smP0, smP1, a_acc);
  anorm_kernel<<<2,1024,0,stream>>>(a_acc, (float*)d_out + 1048576);
}